// Round 1
// 127.887 us; speedup vs baseline: 1.0108x; 1.0108x over previous
//
#include <hip/hip_runtime.h>
#include <math.h>

#define D_FEAT 64
typedef _Float16 v8h __attribute__((ext_vector_type(8)));
typedef float v4f __attribute__((ext_vector_type(4)));
typedef _Float16 h2 __attribute__((ext_vector_type(2)));

__device__ __forceinline__ v8h u2h8(uint4 u) { v8h v; __builtin_memcpy(&v, &u, 16); return v; }

// ---- K0 (merged): blocks [0,nb_prep): per-node rsqrt-norm + f16 copy of x.
//      blocks [nb_prep,..): CSR row offsets via boundary scatter (rows sorted).
__global__ __launch_bounds__(256)
void agnn_prep(const float* __restrict__ x, float* __restrict__ rn,
               uint2* __restrict__ xh, const int* __restrict__ edge_row,
               int* __restrict__ row_ptr, int n_nodes, int n_edges, int nb_prep) {
    if ((int)blockIdx.x < nb_prep) {
        int t = blockIdx.x * blockDim.x + threadIdx.x;
        int node = t >> 4;
        if (node >= n_nodes) return;
        int l4 = t & 15;
        float4 v = ((const float4*)x)[node * 16 + l4];
        float ss = v.x*v.x + v.y*v.y + v.z*v.z + v.w*v.w;
        #pragma unroll
        for (int off = 1; off < 16; off <<= 1) ss += __shfl_xor(ss, off, 64);
        if (l4 == 0) rn[node] = ss > 0.f ? rsqrtf(ss) : 0.f;
        h2 h0 = {(_Float16)v.x, (_Float16)v.y};
        h2 h1 = {(_Float16)v.z, (_Float16)v.w};
        uint2 u;
        __builtin_memcpy(&u.x, &h0, 4);
        __builtin_memcpy(&u.y, &h1, 4);
        xh[node * 16 + l4] = u;
    } else {
        int e = (blockIdx.x - nb_prep) * blockDim.x + threadIdx.x;
        if (e >= n_edges) return;
        int r1 = edge_row[e];
        int r0 = (e == 0) ? -1 : edge_row[e - 1];
        for (int r = r0 + 1; r <= r1; ++r) row_ptr[r] = e;
        if (e == n_edges - 1)
            for (int r = r1 + 1; r <= n_nodes; ++r) row_ptr[r] = n_edges;
    }
}

// ---- K1: block-sparse flash-style fused kernel (software-pipelined) ----
// One WAVE per tile of 16 consecutive nodes (CSR edges contiguous per tile).
// 1-deep pipeline: at chunk i, issue chunk i+1's edge_col loads before the QK
// MFMAs, and chunk i+1's xh/rn gathers before the w/P/PV phase, so gather
// latency hides under compute.  Row membership comes from row_ptr bounds
// (b0..b4 per lane) instead of a per-edge edge_row gather.
// Layouts per guide Sec.3: C/D col=lane&15,row=quad*4+reg; A m=lane&15,k=quad*8+j.
#define XCP_PITCH 144
#define P_PITCH    80
#define WAVE_LDS  (32 * XCP_PITCH + 16 * P_PITCH)

__global__ __launch_bounds__(256)
void agnn_fused(const float* __restrict__ beta_p,
                const int* __restrict__ edge_col,
                const int* __restrict__ row_ptr,
                const float* __restrict__ rn,
                const uint4* __restrict__ xh4,
                float* __restrict__ out, int n_nodes) {
    __shared__ char lds_raw[4 * WAVE_LDS];
    int wid  = threadIdx.x >> 6;
    int lane = threadIdx.x & 63;
    int q    = lane >> 4;
    int lo4  = lane & 15;
    char* XCP = lds_raw + wid * WAVE_LDS;
    char* PL  = XCP + 32 * XCP_PITCH;

    int tile = blockIdx.x * 4 + wid;
    int t0 = tile * 16;
    if (t0 >= n_nodes) return;

    int qnode = t0 + lo4; if (qnode >= n_nodes) qnode = n_nodes - 1;
    v8h a0 = u2h8(xh4[(size_t)qnode * 8 + q]);
    v8h a1 = u2h8(xh4[(size_t)qnode * 8 + 4 + q]);

    float beta  = beta_p[0];
    float shift = fabsf(beta);
    int rb = t0 + q * 4;
    float brn0, brn1, brn2, brn3;
    if (t0 + 16 <= n_nodes) {
        float4 rq = *(const float4*)(rn + rb);
        brn0 = beta * rq.x; brn1 = beta * rq.y; brn2 = beta * rq.z; brn3 = beta * rq.w;
    } else {
        brn0 = beta * rn[min(rb + 0, n_nodes - 1)];
        brn1 = beta * rn[min(rb + 1, n_nodes - 1)];
        brn2 = beta * rn[min(rb + 2, n_nodes - 1)];
        brn3 = beta * rn[min(rb + 3, n_nodes - 1)];
    }

    int es   = row_ptr[t0];
    int tend = t0 + 16; if (tend > n_nodes) tend = n_nodes;
    int L    = row_ptr[tend] - es;

    // Per-lane row bounds: row rb+j owns edge slots [b_j, b_{j+1}).  All b<=L,
    // so the bounds check also subsumes the idx<L validity check.
    int b0 = row_ptr[min(rb + 0, n_nodes)] - es;
    int b1 = row_ptr[min(rb + 1, n_nodes)] - es;
    int b2 = row_ptr[min(rb + 2, n_nodes)] - es;
    int b3 = row_ptr[min(rb + 3, n_nodes)] - es;
    int b4 = row_ptr[min(rb + 4, n_nodes)] - es;

    v4f o0 = {0,0,0,0}, o1 = {0,0,0,0}, o2 = {0,0,0,0}, o3 = {0,0,0,0};
    float l0 = 0.f, l1 = 0.f, l2 = 0.f, l3 = 0.f;
    unsigned int selp = (lo4 & 1) ? 0x07060302u : 0x05040100u;

    int nch = (L + 31) >> 5;
    if (nch > 0) {
        // Prologue: chunk 0 indices + gathers.
        int cc0, cc1;
        {
            int i0 = lo4, i1 = lo4 + 16;
            cc0 = edge_col[es + (i0 < L ? i0 : 0)];
            cc1 = edge_col[es + (i1 < L ? i1 : 0)];
        }
        float rc0 = rn[cc0], rc1 = rn[cc1];
        uint4 A00 = xh4[(size_t)cc0 * 8 + q];
        uint4 A01 = xh4[(size_t)cc0 * 8 + 4 + q];
        uint4 A10 = xh4[(size_t)cc1 * 8 + q];
        uint4 A11 = xh4[(size_t)cc1 * 8 + 4 + q];

        for (int ch = 0; ch < nch; ++ch) {
            int base = ch << 5;
            bool more = (ch + 1) < nch;

            // Prefetch next chunk's column indices (latency hides under QK).
            int nc0, nc1;
            if (more) {
                int i0 = base + 32 + lo4, i1 = i0 + 16;
                nc0 = edge_col[es + (i0 < L ? i0 : 0)];
                nc1 = edge_col[es + (i1 < L ? i1 : 0)];
            } else { nc0 = cc0; nc1 = cc1; }

            v4f z0 = {0,0,0,0};
            z0 = __builtin_amdgcn_mfma_f32_16x16x32_f16(a0, u2h8(A00), z0, 0, 0, 0);
            z0 = __builtin_amdgcn_mfma_f32_16x16x32_f16(a1, u2h8(A01), z0, 0, 0, 0);
            v4f z1 = {0,0,0,0};
            z1 = __builtin_amdgcn_mfma_f32_16x16x32_f16(a0, u2h8(A10), z1, 0, 0, 0);
            z1 = __builtin_amdgcn_mfma_f32_16x16x32_f16(a1, u2h8(A11), z1, 0, 0, 0);

            {
                unsigned int colA = lo4 * 4, colB = (16 + lo4) * 4;
                char* pA = XCP + (4 * q) * XCP_PITCH;
                char* pB = XCP + (16 + 4 * q) * XCP_PITCH;
                *(unsigned int*)(pA + 0 * XCP_PITCH + colA) = A00.x;
                *(unsigned int*)(pA + 1 * XCP_PITCH + colA) = A00.y;
                *(unsigned int*)(pA + 2 * XCP_PITCH + colA) = A00.z;
                *(unsigned int*)(pA + 3 * XCP_PITCH + colA) = A00.w;
                *(unsigned int*)(pB + 0 * XCP_PITCH + colA) = A01.x;
                *(unsigned int*)(pB + 1 * XCP_PITCH + colA) = A01.y;
                *(unsigned int*)(pB + 2 * XCP_PITCH + colA) = A01.z;
                *(unsigned int*)(pB + 3 * XCP_PITCH + colA) = A01.w;
                *(unsigned int*)(pA + 0 * XCP_PITCH + colB) = A10.x;
                *(unsigned int*)(pA + 1 * XCP_PITCH + colB) = A10.y;
                *(unsigned int*)(pA + 2 * XCP_PITCH + colB) = A10.z;
                *(unsigned int*)(pA + 3 * XCP_PITCH + colB) = A10.w;
                *(unsigned int*)(pB + 0 * XCP_PITCH + colB) = A11.x;
                *(unsigned int*)(pB + 1 * XCP_PITCH + colB) = A11.y;
                *(unsigned int*)(pB + 2 * XCP_PITCH + colB) = A11.z;
                *(unsigned int*)(pB + 3 * XCP_PITCH + colB) = A11.w;
            }

            // Prefetch next chunk's features + norms (latency hides under
            // w/exp + P relay + PV MFMAs below; waited at next iter's QK).
            float nr0, nr1; uint4 B00, B01, B10, B11;
            if (more) {
                nr0 = rn[nc0]; nr1 = rn[nc1];
                B00 = xh4[(size_t)nc0 * 8 + q];
                B01 = xh4[(size_t)nc0 * 8 + 4 + q];
                B10 = xh4[(size_t)nc1 * 8 + q];
                B11 = xh4[(size_t)nc1 * 8 + 4 + q];
            } else {
                nr0 = rc0; nr1 = rc1;
                B00 = A00; B01 = A01; B10 = A10; B11 = A11;
            }

            int i0g = base + lo4, i1g = i0g + 16;
            float w00 = (i0g >= b0 && i0g < b1) ? __expf(brn0 * rc0 * z0[0] - shift) : 0.f;
            float w01 = (i0g >= b1 && i0g < b2) ? __expf(brn1 * rc0 * z0[1] - shift) : 0.f;
            float w02 = (i0g >= b2 && i0g < b3) ? __expf(brn2 * rc0 * z0[2] - shift) : 0.f;
            float w03 = (i0g >= b3 && i0g < b4) ? __expf(brn3 * rc0 * z0[3] - shift) : 0.f;
            float w10 = (i1g >= b0 && i1g < b1) ? __expf(brn0 * rc1 * z1[0] - shift) : 0.f;
            float w11 = (i1g >= b1 && i1g < b2) ? __expf(brn1 * rc1 * z1[1] - shift) : 0.f;
            float w12 = (i1g >= b2 && i1g < b3) ? __expf(brn2 * rc1 * z1[2] - shift) : 0.f;
            float w13 = (i1g >= b3 && i1g < b4) ? __expf(brn3 * rc1 * z1[3] - shift) : 0.f;
            l0 += w00 + w10; l1 += w01 + w11; l2 += w02 + w12; l3 += w03 + w13;

            {
                unsigned int cA = lo4 * 2, cB = (16 + lo4) * 2;
                char* pm = PL + (q * 4) * P_PITCH;
                *(_Float16*)(pm + 0 * P_PITCH + cA) = (_Float16)w00;
                *(_Float16*)(pm + 1 * P_PITCH + cA) = (_Float16)w01;
                *(_Float16*)(pm + 2 * P_PITCH + cA) = (_Float16)w02;
                *(_Float16*)(pm + 3 * P_PITCH + cA) = (_Float16)w03;
                *(_Float16*)(pm + 0 * P_PITCH + cB) = (_Float16)w10;
                *(_Float16*)(pm + 1 * P_PITCH + cB) = (_Float16)w11;
                *(_Float16*)(pm + 2 * P_PITCH + cB) = (_Float16)w12;
                *(_Float16*)(pm + 3 * P_PITCH + cB) = (_Float16)w13;
            }

            v8h pah = u2h8(*(const uint4*)(PL + lo4 * P_PITCH + q * 16));
            {
                const char* rp = XCP + (0 + (lo4 >> 1)) * XCP_PITCH + q * 32;
                uint4 da = *(const uint4*)rp;
                uint4 db = *(const uint4*)(rp + 16);
                uint4 bb = { __builtin_amdgcn_perm(da.y, da.x, selp),
                             __builtin_amdgcn_perm(da.w, da.z, selp),
                             __builtin_amdgcn_perm(db.y, db.x, selp),
                             __builtin_amdgcn_perm(db.w, db.z, selp) };
                o0 = __builtin_amdgcn_mfma_f32_16x16x32_f16(pah, u2h8(bb), o0, 0, 0, 0);
            }
            {
                const char* rp = XCP + (8 + (lo4 >> 1)) * XCP_PITCH + q * 32;
                uint4 da = *(const uint4*)rp;
                uint4 db = *(const uint4*)(rp + 16);
                uint4 bb = { __builtin_amdgcn_perm(da.y, da.x, selp),
                             __builtin_amdgcn_perm(da.w, da.z, selp),
                             __builtin_amdgcn_perm(db.y, db.x, selp),
                             __builtin_amdgcn_perm(db.w, db.z, selp) };
                o1 = __builtin_amdgcn_mfma_f32_16x16x32_f16(pah, u2h8(bb), o1, 0, 0, 0);
            }
            {
                const char* rp = XCP + (16 + (lo4 >> 1)) * XCP_PITCH + q * 32;
                uint4 da = *(const uint4*)rp;
                uint4 db = *(const uint4*)(rp + 16);
                uint4 bb = { __builtin_amdgcn_perm(da.y, da.x, selp),
                             __builtin_amdgcn_perm(da.w, da.z, selp),
                             __builtin_amdgcn_perm(db.y, db.x, selp),
                             __builtin_amdgcn_perm(db.w, db.z, selp) };
                o2 = __builtin_amdgcn_mfma_f32_16x16x32_f16(pah, u2h8(bb), o2, 0, 0, 0);
            }
            {
                const char* rp = XCP + (24 + (lo4 >> 1)) * XCP_PITCH + q * 32;
                uint4 da = *(const uint4*)rp;
                uint4 db = *(const uint4*)(rp + 16);
                uint4 bb = { __builtin_amdgcn_perm(da.y, da.x, selp),
                             __builtin_amdgcn_perm(da.w, da.z, selp),
                             __builtin_amdgcn_perm(db.y, db.x, selp),
                             __builtin_amdgcn_perm(db.w, db.z, selp) };
                o3 = __builtin_amdgcn_mfma_f32_16x16x32_f16(pah, u2h8(bb), o3, 0, 0, 0);
            }

            // Rotate pipeline state.
            cc0 = nc0; cc1 = nc1; rc0 = nr0; rc1 = nr1;
            A00 = B00; A01 = B01; A10 = B10; A11 = B11;
        }
    }

    #pragma unroll
    for (int off = 1; off < 16; off <<= 1) {
        l0 += __shfl_xor(l0, off, 64);
        l1 += __shfl_xor(l1, off, 64);
        l2 += __shfl_xor(l2, off, 64);
        l3 += __shfl_xor(l3, off, 64);
    }
    float i0 = l0 > 0.f ? 1.f / l0 : 0.f;
    float i1 = l1 > 0.f ? 1.f / l1 : 0.f;
    float i2 = l2 > 0.f ? 1.f / l2 : 0.f;
    float i3 = l3 > 0.f ? 1.f / l3 : 0.f;

    int m0 = rb;
    if (m0 + 0 < n_nodes) { float* p = out + (size_t)(m0 + 0) * 64 + lo4;
        p[0] = o0[0]*i0; p[16] = o1[0]*i0; p[32] = o2[0]*i0; p[48] = o3[0]*i0; }
    if (m0 + 1 < n_nodes) { float* p = out + (size_t)(m0 + 1) * 64 + lo4;
        p[0] = o0[1]*i1; p[16] = o1[1]*i1; p[32] = o2[1]*i1; p[48] = o3[1]*i1; }
    if (m0 + 2 < n_nodes) { float* p = out + (size_t)(m0 + 2) * 64 + lo4;
        p[0] = o0[2]*i2; p[16] = o1[2]*i2; p[32] = o2[2]*i2; p[48] = o3[2]*i2; }
    if (m0 + 3 < n_nodes) { float* p = out + (size_t)(m0 + 3) * 64 + lo4;
        p[0] = o0[3]*i3; p[16] = o1[3]*i3; p[32] = o2[3]*i3; p[48] = o3[3]*i3; }
}

extern "C" void kernel_launch(void* const* d_in, const int* in_sizes, int n_in,
                              void* d_out, int out_size, void* d_ws, size_t ws_size,
                              hipStream_t stream) {
    const float* x        = (const float*)d_in[0];
    const float* beta     = (const float*)d_in[1];
    const int*   edge_row = (const int*)d_in[2];
    const int*   edge_col = (const int*)d_in[3];
    float* out = (float*)d_out;

    int n_nodes = in_sizes[0] / D_FEAT;
    int n_edges = in_sizes[2];

    char* ws = (char*)d_ws;
    float* rn = (float*)ws;
    size_t off0 = ((size_t)n_nodes * sizeof(float) + 255) & ~(size_t)255;
    int* row_ptr = (int*)(ws + off0);
    size_t off1 = off0 + (((size_t)(n_nodes + 1) * sizeof(int) + 255) & ~(size_t)255);
    uint2* xh = (uint2*)(ws + off1);

    {
        int nb_prep = (n_nodes * 16 + 255) / 256;
        int nb_rp   = (n_edges + 255) / 256;
        agnn_prep<<<nb_prep + nb_rp, 256, 0, stream>>>(
            x, rn, xh, edge_row, row_ptr, n_nodes, n_edges, nb_prep);
    }
    {
        int tiles  = (n_nodes + 15) / 16;
        int blocks = (tiles + 3) / 4;
        agnn_fused<<<blocks, 256, 0, stream>>>(beta, edge_col, row_ptr,
                                               rn, (const uint4*)xh, out, n_nodes);
    }
}

// Round 2
// 127.275 us; speedup vs baseline: 1.0156x; 1.0048x over previous
//
#include <hip/hip_runtime.h>
#include <math.h>

#define D_FEAT 64
typedef _Float16 v8h __attribute__((ext_vector_type(8)));
typedef float v4f __attribute__((ext_vector_type(4)));
typedef _Float16 h2 __attribute__((ext_vector_type(2)));

__device__ __forceinline__ v8h u2h8(uint4 u) { v8h v; __builtin_memcpy(&v, &u, 16); return v; }

// ---- K0 (merged): blocks [0,nb_prep): per-node rsqrt-norm + f16 copy of x.
//      blocks [nb_prep,..): CSR row offsets via boundary scatter (rows sorted).
__global__ __launch_bounds__(256)
void agnn_prep(const float* __restrict__ x, float* __restrict__ rn,
               uint2* __restrict__ xh, const int* __restrict__ edge_row,
               int* __restrict__ row_ptr, int n_nodes, int n_edges, int nb_prep) {
    if ((int)blockIdx.x < nb_prep) {
        int t = blockIdx.x * blockDim.x + threadIdx.x;
        int node = t >> 4;
        if (node >= n_nodes) return;
        int l4 = t & 15;
        float4 v = ((const float4*)x)[node * 16 + l4];
        float ss = v.x*v.x + v.y*v.y + v.z*v.z + v.w*v.w;
        #pragma unroll
        for (int off = 1; off < 16; off <<= 1) ss += __shfl_xor(ss, off, 64);
        if (l4 == 0) rn[node] = ss > 0.f ? rsqrtf(ss) : 0.f;
        h2 h0 = {(_Float16)v.x, (_Float16)v.y};
        h2 h1 = {(_Float16)v.z, (_Float16)v.w};
        uint2 u;
        __builtin_memcpy(&u.x, &h0, 4);
        __builtin_memcpy(&u.y, &h1, 4);
        xh[node * 16 + l4] = u;
    } else {
        int e = (blockIdx.x - nb_prep) * blockDim.x + threadIdx.x;
        if (e >= n_edges) return;
        int r1 = edge_row[e];
        int r0 = (e == 0) ? -1 : edge_row[e - 1];
        for (int r = r0 + 1; r <= r1; ++r) row_ptr[r] = e;
        if (e == n_edges - 1)
            for (int r = r1 + 1; r <= n_nodes; ++r) row_ptr[r] = n_edges;
    }
}

// ---- K1: block-sparse flash-style fused kernel ----
// ONE WAVE PER BLOCK, one tile of 16 nodes per block.  The kernel has no
// __syncthreads and wave-private LDS, so 4-wave blocks only coarsened the
// residency granule: 23.5KB-LDS/256-thr blocks ran in 2-3 residency rounds
// with a 4-tile straggler tail (time-avg occupancy 28%).  64-thr/5.9KB
// blocks make the tail one tile and raise resident waves/SIMD.
// 1-deep pipeline: chunk i+1's edge_col before QK, xh/rn gathers before PV.
// Row membership from row_ptr bounds (b0..b4), subsumes idx<L check.
// Layouts per guide Sec.3: C/D col=lane&15,row=quad*4+reg; A m=lane&15,k=quad*8+j.
#define XCP_PITCH 144
#define P_PITCH    80
#define WAVE_LDS  (32 * XCP_PITCH + 16 * P_PITCH)

__global__ __launch_bounds__(64)
void agnn_fused(const float* __restrict__ beta_p,
                const int* __restrict__ edge_col,
                const int* __restrict__ row_ptr,
                const float* __restrict__ rn,
                const uint4* __restrict__ xh4,
                float* __restrict__ out, int n_nodes) {
    __shared__ char lds_raw[WAVE_LDS];
    int lane = threadIdx.x & 63;
    int q    = lane >> 4;
    int lo4  = lane & 15;
    char* XCP = lds_raw;
    char* PL  = XCP + 32 * XCP_PITCH;

    int tile = blockIdx.x;
    int t0 = tile * 16;
    if (t0 >= n_nodes) return;

    int qnode = t0 + lo4; if (qnode >= n_nodes) qnode = n_nodes - 1;
    v8h a0 = u2h8(xh4[(size_t)qnode * 8 + q]);
    v8h a1 = u2h8(xh4[(size_t)qnode * 8 + 4 + q]);

    float beta  = beta_p[0];
    float shift = fabsf(beta);
    int rb = t0 + q * 4;
    float brn0, brn1, brn2, brn3;
    if (t0 + 16 <= n_nodes) {
        float4 rq = *(const float4*)(rn + rb);
        brn0 = beta * rq.x; brn1 = beta * rq.y; brn2 = beta * rq.z; brn3 = beta * rq.w;
    } else {
        brn0 = beta * rn[min(rb + 0, n_nodes - 1)];
        brn1 = beta * rn[min(rb + 1, n_nodes - 1)];
        brn2 = beta * rn[min(rb + 2, n_nodes - 1)];
        brn3 = beta * rn[min(rb + 3, n_nodes - 1)];
    }

    int es   = row_ptr[t0];
    int tend = t0 + 16; if (tend > n_nodes) tend = n_nodes;
    int L    = row_ptr[tend] - es;

    // Per-lane row bounds: row rb+j owns edge slots [b_j, b_{j+1}).  All b<=L,
    // so the bounds check also subsumes the idx<L validity check.
    int b0 = row_ptr[min(rb + 0, n_nodes)] - es;
    int b1 = row_ptr[min(rb + 1, n_nodes)] - es;
    int b2 = row_ptr[min(rb + 2, n_nodes)] - es;
    int b3 = row_ptr[min(rb + 3, n_nodes)] - es;
    int b4 = row_ptr[min(rb + 4, n_nodes)] - es;

    v4f o0 = {0,0,0,0}, o1 = {0,0,0,0}, o2 = {0,0,0,0}, o3 = {0,0,0,0};
    float l0 = 0.f, l1 = 0.f, l2 = 0.f, l3 = 0.f;
    unsigned int selp = (lo4 & 1) ? 0x07060302u : 0x05040100u;

    int nch = (L + 31) >> 5;
    if (nch > 0) {
        // Prologue: chunk 0 indices + gathers.
        int cc0, cc1;
        {
            int i0 = lo4, i1 = lo4 + 16;
            cc0 = edge_col[es + (i0 < L ? i0 : 0)];
            cc1 = edge_col[es + (i1 < L ? i1 : 0)];
        }
        float rc0 = rn[cc0], rc1 = rn[cc1];
        uint4 A00 = xh4[(size_t)cc0 * 8 + q];
        uint4 A01 = xh4[(size_t)cc0 * 8 + 4 + q];
        uint4 A10 = xh4[(size_t)cc1 * 8 + q];
        uint4 A11 = xh4[(size_t)cc1 * 8 + 4 + q];

        for (int ch = 0; ch < nch; ++ch) {
            int base = ch << 5;
            bool more = (ch + 1) < nch;

            // Prefetch next chunk's column indices (latency hides under QK).
            int nc0, nc1;
            if (more) {
                int i0 = base + 32 + lo4, i1 = i0 + 16;
                nc0 = edge_col[es + (i0 < L ? i0 : 0)];
                nc1 = edge_col[es + (i1 < L ? i1 : 0)];
            } else { nc0 = cc0; nc1 = cc1; }

            v4f z0 = {0,0,0,0};
            z0 = __builtin_amdgcn_mfma_f32_16x16x32_f16(a0, u2h8(A00), z0, 0, 0, 0);
            z0 = __builtin_amdgcn_mfma_f32_16x16x32_f16(a1, u2h8(A01), z0, 0, 0, 0);
            v4f z1 = {0,0,0,0};
            z1 = __builtin_amdgcn_mfma_f32_16x16x32_f16(a0, u2h8(A10), z1, 0, 0, 0);
            z1 = __builtin_amdgcn_mfma_f32_16x16x32_f16(a1, u2h8(A11), z1, 0, 0, 0);

            {
                unsigned int colA = lo4 * 4, colB = (16 + lo4) * 4;
                char* pA = XCP + (4 * q) * XCP_PITCH;
                char* pB = XCP + (16 + 4 * q) * XCP_PITCH;
                *(unsigned int*)(pA + 0 * XCP_PITCH + colA) = A00.x;
                *(unsigned int*)(pA + 1 * XCP_PITCH + colA) = A00.y;
                *(unsigned int*)(pA + 2 * XCP_PITCH + colA) = A00.z;
                *(unsigned int*)(pA + 3 * XCP_PITCH + colA) = A00.w;
                *(unsigned int*)(pB + 0 * XCP_PITCH + colA) = A01.x;
                *(unsigned int*)(pB + 1 * XCP_PITCH + colA) = A01.y;
                *(unsigned int*)(pB + 2 * XCP_PITCH + colA) = A01.z;
                *(unsigned int*)(pB + 3 * XCP_PITCH + colA) = A01.w;
                *(unsigned int*)(pA + 0 * XCP_PITCH + colB) = A10.x;
                *(unsigned int*)(pA + 1 * XCP_PITCH + colB) = A10.y;
                *(unsigned int*)(pA + 2 * XCP_PITCH + colB) = A10.z;
                *(unsigned int*)(pA + 3 * XCP_PITCH + colB) = A10.w;
                *(unsigned int*)(pB + 0 * XCP_PITCH + colB) = A11.x;
                *(unsigned int*)(pB + 1 * XCP_PITCH + colB) = A11.y;
                *(unsigned int*)(pB + 2 * XCP_PITCH + colB) = A11.z;
                *(unsigned int*)(pB + 3 * XCP_PITCH + colB) = A11.w;
            }

            // Prefetch next chunk's features + norms (latency hides under
            // w/exp + P relay + PV MFMAs below; waited at next iter's QK).
            float nr0, nr1; uint4 B00, B01, B10, B11;
            if (more) {
                nr0 = rn[nc0]; nr1 = rn[nc1];
                B00 = xh4[(size_t)nc0 * 8 + q];
                B01 = xh4[(size_t)nc0 * 8 + 4 + q];
                B10 = xh4[(size_t)nc1 * 8 + q];
                B11 = xh4[(size_t)nc1 * 8 + 4 + q];
            } else {
                nr0 = rc0; nr1 = rc1;
                B00 = A00; B01 = A01; B10 = A10; B11 = A11;
            }

            int i0g = base + lo4, i1g = i0g + 16;
            float w00 = (i0g >= b0 && i0g < b1) ? __expf(brn0 * rc0 * z0[0] - shift) : 0.f;
            float w01 = (i0g >= b1 && i0g < b2) ? __expf(brn1 * rc0 * z0[1] - shift) : 0.f;
            float w02 = (i0g >= b2 && i0g < b3) ? __expf(brn2 * rc0 * z0[2] - shift) : 0.f;
            float w03 = (i0g >= b3 && i0g < b4) ? __expf(brn3 * rc0 * z0[3] - shift) : 0.f;
            float w10 = (i1g >= b0 && i1g < b1) ? __expf(brn0 * rc1 * z1[0] - shift) : 0.f;
            float w11 = (i1g >= b1 && i1g < b2) ? __expf(brn1 * rc1 * z1[1] - shift) : 0.f;
            float w12 = (i1g >= b2 && i1g < b3) ? __expf(brn2 * rc1 * z1[2] - shift) : 0.f;
            float w13 = (i1g >= b3 && i1g < b4) ? __expf(brn3 * rc1 * z1[3] - shift) : 0.f;
            l0 += w00 + w10; l1 += w01 + w11; l2 += w02 + w12; l3 += w03 + w13;

            {
                unsigned int cA = lo4 * 2, cB = (16 + lo4) * 2;
                char* pm = PL + (q * 4) * P_PITCH;
                *(_Float16*)(pm + 0 * P_PITCH + cA) = (_Float16)w00;
                *(_Float16*)(pm + 1 * P_PITCH + cA) = (_Float16)w01;
                *(_Float16*)(pm + 2 * P_PITCH + cA) = (_Float16)w02;
                *(_Float16*)(pm + 3 * P_PITCH + cA) = (_Float16)w03;
                *(_Float16*)(pm + 0 * P_PITCH + cB) = (_Float16)w10;
                *(_Float16*)(pm + 1 * P_PITCH + cB) = (_Float16)w11;
                *(_Float16*)(pm + 2 * P_PITCH + cB) = (_Float16)w12;
                *(_Float16*)(pm + 3 * P_PITCH + cB) = (_Float16)w13;
            }

            v8h pah = u2h8(*(const uint4*)(PL + lo4 * P_PITCH + q * 16));
            {
                const char* rp = XCP + (0 + (lo4 >> 1)) * XCP_PITCH + q * 32;
                uint4 da = *(const uint4*)rp;
                uint4 db = *(const uint4*)(rp + 16);
                uint4 bb = { __builtin_amdgcn_perm(da.y, da.x, selp),
                             __builtin_amdgcn_perm(da.w, da.z, selp),
                             __builtin_amdgcn_perm(db.y, db.x, selp),
                             __builtin_amdgcn_perm(db.w, db.z, selp) };
                o0 = __builtin_amdgcn_mfma_f32_16x16x32_f16(pah, u2h8(bb), o0, 0, 0, 0);
            }
            {
                const char* rp = XCP + (8 + (lo4 >> 1)) * XCP_PITCH + q * 32;
                uint4 da = *(const uint4*)rp;
                uint4 db = *(const uint4*)(rp + 16);
                uint4 bb = { __builtin_amdgcn_perm(da.y, da.x, selp),
                             __builtin_amdgcn_perm(da.w, da.z, selp),
                             __builtin_amdgcn_perm(db.y, db.x, selp),
                             __builtin_amdgcn_perm(db.w, db.z, selp) };
                o1 = __builtin_amdgcn_mfma_f32_16x16x32_f16(pah, u2h8(bb), o1, 0, 0, 0);
            }
            {
                const char* rp = XCP + (16 + (lo4 >> 1)) * XCP_PITCH + q * 32;
                uint4 da = *(const uint4*)rp;
                uint4 db = *(const uint4*)(rp + 16);
                uint4 bb = { __builtin_amdgcn_perm(da.y, da.x, selp),
                             __builtin_amdgcn_perm(da.w, da.z, selp),
                             __builtin_amdgcn_perm(db.y, db.x, selp),
                             __builtin_amdgcn_perm(db.w, db.z, selp) };
                o2 = __builtin_amdgcn_mfma_f32_16x16x32_f16(pah, u2h8(bb), o2, 0, 0, 0);
            }
            {
                const char* rp = XCP + (24 + (lo4 >> 1)) * XCP_PITCH + q * 32;
                uint4 da = *(const uint4*)rp;
                uint4 db = *(const uint4*)(rp + 16);
                uint4 bb = { __builtin_amdgcn_perm(da.y, da.x, selp),
                             __builtin_amdgcn_perm(da.w, da.z, selp),
                             __builtin_amdgcn_perm(db.y, db.x, selp),
                             __builtin_amdgcn_perm(db.w, db.z, selp) };
                o3 = __builtin_amdgcn_mfma_f32_16x16x32_f16(pah, u2h8(bb), o3, 0, 0, 0);
            }

            // Rotate pipeline state.
            cc0 = nc0; cc1 = nc1; rc0 = nr0; rc1 = nr1;
            A00 = B00; A01 = B01; A10 = B10; A11 = B11;
        }
    }

    #pragma unroll
    for (int off = 1; off < 16; off <<= 1) {
        l0 += __shfl_xor(l0, off, 64);
        l1 += __shfl_xor(l1, off, 64);
        l2 += __shfl_xor(l2, off, 64);
        l3 += __shfl_xor(l3, off, 64);
    }
    float i0 = l0 > 0.f ? 1.f / l0 : 0.f;
    float i1 = l1 > 0.f ? 1.f / l1 : 0.f;
    float i2 = l2 > 0.f ? 1.f / l2 : 0.f;
    float i3 = l3 > 0.f ? 1.f / l3 : 0.f;

    int m0 = rb;
    if (m0 + 0 < n_nodes) { float* p = out + (size_t)(m0 + 0) * 64 + lo4;
        p[0] = o0[0]*i0; p[16] = o1[0]*i0; p[32] = o2[0]*i0; p[48] = o3[0]*i0; }
    if (m0 + 1 < n_nodes) { float* p = out + (size_t)(m0 + 1) * 64 + lo4;
        p[0] = o0[1]*i1; p[16] = o1[1]*i1; p[32] = o2[1]*i1; p[48] = o3[1]*i1; }
    if (m0 + 2 < n_nodes) { float* p = out + (size_t)(m0 + 2) * 64 + lo4;
        p[0] = o0[2]*i2; p[16] = o1[2]*i2; p[32] = o2[2]*i2; p[48] = o3[2]*i2; }
    if (m0 + 3 < n_nodes) { float* p = out + (size_t)(m0 + 3) * 64 + lo4;
        p[0] = o0[3]*i3; p[16] = o1[3]*i3; p[32] = o2[3]*i3; p[48] = o3[3]*i3; }
}

extern "C" void kernel_launch(void* const* d_in, const int* in_sizes, int n_in,
                              void* d_out, int out_size, void* d_ws, size_t ws_size,
                              hipStream_t stream) {
    const float* x        = (const float*)d_in[0];
    const float* beta     = (const float*)d_in[1];
    const int*   edge_row = (const int*)d_in[2];
    const int*   edge_col = (const int*)d_in[3];
    float* out = (float*)d_out;

    int n_nodes = in_sizes[0] / D_FEAT;
    int n_edges = in_sizes[2];

    char* ws = (char*)d_ws;
    float* rn = (float*)ws;
    size_t off0 = ((size_t)n_nodes * sizeof(float) + 255) & ~(size_t)255;
    int* row_ptr = (int*)(ws + off0);
    size_t off1 = off0 + (((size_t)(n_nodes + 1) * sizeof(int) + 255) & ~(size_t)255);
    uint2* xh = (uint2*)(ws + off1);

    {
        int nb_prep = (n_nodes * 16 + 255) / 256;
        int nb_rp   = (n_edges + 255) / 256;
        agnn_prep<<<nb_prep + nb_rp, 256, 0, stream>>>(
            x, rn, xh, edge_row, row_ptr, n_nodes, n_edges, nb_prep);
    }
    {
        int tiles = (n_nodes + 15) / 16;
        agnn_fused<<<tiles, 64, 0, stream>>>(beta, edge_col, row_ptr,
                                             rn, (const uint4*)xh, out, n_nodes);
    }
}

// Round 3
// 125.447 us; speedup vs baseline: 1.0304x; 1.0146x over previous
//
#include <hip/hip_runtime.h>
#include <math.h>

#define D_FEAT 64
typedef _Float16 v8h __attribute__((ext_vector_type(8)));
typedef float v4f __attribute__((ext_vector_type(4)));
typedef _Float16 h2 __attribute__((ext_vector_type(2)));

__device__ __forceinline__ v8h u2h8(uint4 u) { v8h v; __builtin_memcpy(&v, &u, 16); return v; }

// ---- K0 (merged): blocks [0,nb_prep): per-node rsqrt-norm + f16 copy of x.
//      blocks [nb_prep,..): CSR row offsets via boundary scatter (rows sorted).
__global__ __launch_bounds__(256)
void agnn_prep(const float* __restrict__ x, float* __restrict__ rn,
               uint2* __restrict__ xh, const int* __restrict__ edge_row,
               int* __restrict__ row_ptr, int n_nodes, int n_edges, int nb_prep) {
    if ((int)blockIdx.x < nb_prep) {
        int t = blockIdx.x * blockDim.x + threadIdx.x;
        int node = t >> 4;
        if (node >= n_nodes) return;
        int l4 = t & 15;
        float4 v = ((const float4*)x)[node * 16 + l4];
        float ss = v.x*v.x + v.y*v.y + v.z*v.z + v.w*v.w;
        #pragma unroll
        for (int off = 1; off < 16; off <<= 1) ss += __shfl_xor(ss, off, 64);
        if (l4 == 0) rn[node] = ss > 0.f ? rsqrtf(ss) : 0.f;
        h2 h0 = {(_Float16)v.x, (_Float16)v.y};
        h2 h1 = {(_Float16)v.z, (_Float16)v.w};
        uint2 u;
        __builtin_memcpy(&u.x, &h0, 4);
        __builtin_memcpy(&u.y, &h1, 4);
        xh[node * 16 + l4] = u;
    } else {
        int e = (blockIdx.x - nb_prep) * blockDim.x + threadIdx.x;
        if (e >= n_edges) return;
        int r1 = edge_row[e];
        int r0 = (e == 0) ? -1 : edge_row[e - 1];
        for (int r = r0 + 1; r <= r1; ++r) row_ptr[r] = e;
        if (e == n_edges - 1)
            for (int r = r1 + 1; r <= n_nodes; ++r) row_ptr[r] = n_edges;
    }
}

// ---- K1: block-sparse flash-style fused kernel, 2 cooperating waves/tile ----
// One 128-thread block per tile of 16 nodes.  Wave w processes chunks
// w, w+2, w+4, ... (32 edges each) with private o/l accumulators and
// wave-private LDS; one barrier at the end, wave1 dumps partials to its LDS
// area, wave0 combines + normalizes + stores.  Rationale: 1-wave tiles were
// latency-bound at 2.3 waves/SIMD (WG/CU cap 16); 2-wave tiles halve the
// serial chunk chain and lift the residency cap to ~26 waves/CU.
// Row membership from row_ptr bounds (b0..b4), subsumes idx<L check.
// Layouts per guide Sec.3: C/D col=lane&15,row=quad*4+reg; A m=lane&15,k=quad*8+j.
#define XCP_PITCH 144
#define P_PITCH    80
#define WAVE_LDS  (32 * XCP_PITCH + 16 * P_PITCH)

__global__ __launch_bounds__(128)
void agnn_fused(const float* __restrict__ beta_p,
                const int* __restrict__ edge_col,
                const int* __restrict__ row_ptr,
                const float* __restrict__ rn,
                const uint4* __restrict__ xh4,
                float* __restrict__ out, int n_nodes) {
    __shared__ char lds_raw[2 * WAVE_LDS];
    int wid  = threadIdx.x >> 6;
    int lane = threadIdx.x & 63;
    int q    = lane >> 4;
    int lo4  = lane & 15;
    char* XCP = lds_raw + wid * WAVE_LDS;
    char* PL  = XCP + 32 * XCP_PITCH;

    int tile = blockIdx.x;
    int t0 = tile * 16;

    int qnode = t0 + lo4; if (qnode >= n_nodes) qnode = n_nodes - 1;
    v8h a0 = u2h8(xh4[(size_t)qnode * 8 + q]);
    v8h a1 = u2h8(xh4[(size_t)qnode * 8 + 4 + q]);

    float beta  = beta_p[0];
    float shift = fabsf(beta);
    int rb = t0 + q * 4;
    float brn0, brn1, brn2, brn3;
    if (t0 + 16 <= n_nodes) {
        float4 rq = *(const float4*)(rn + rb);
        brn0 = beta * rq.x; brn1 = beta * rq.y; brn2 = beta * rq.z; brn3 = beta * rq.w;
    } else {
        brn0 = beta * rn[min(rb + 0, n_nodes - 1)];
        brn1 = beta * rn[min(rb + 1, n_nodes - 1)];
        brn2 = beta * rn[min(rb + 2, n_nodes - 1)];
        brn3 = beta * rn[min(rb + 3, n_nodes - 1)];
    }

    int es   = row_ptr[t0];
    int tend = t0 + 16; if (tend > n_nodes) tend = n_nodes;
    int L    = row_ptr[tend] - es;

    // Per-lane row bounds: row rb+j owns edge slots [b_j, b_{j+1}).  All b<=L,
    // so the bounds check also subsumes the idx<L validity check.
    int b0 = row_ptr[min(rb + 0, n_nodes)] - es;
    int b1 = row_ptr[min(rb + 1, n_nodes)] - es;
    int b2 = row_ptr[min(rb + 2, n_nodes)] - es;
    int b3 = row_ptr[min(rb + 3, n_nodes)] - es;
    int b4 = row_ptr[min(rb + 4, n_nodes)] - es;

    v4f o0 = {0,0,0,0}, o1 = {0,0,0,0}, o2 = {0,0,0,0}, o3 = {0,0,0,0};
    float l0 = 0.f, l1 = 0.f, l2 = 0.f, l3 = 0.f;
    unsigned int selp = (lo4 & 1) ? 0x07060302u : 0x05040100u;

    int nch  = (L + 31) >> 5;
    int nchw = (nch > wid) ? ((nch - wid + 1) >> 1) : 0;  // chunks for this wave
    if (nchw > 0) {
        // Prologue: this wave's chunk 0 (global chunk index = wid).
        int cc0, cc1;
        {
            int i0 = (wid << 5) + lo4, i1 = i0 + 16;
            cc0 = edge_col[es + (i0 < L ? i0 : 0)];
            cc1 = edge_col[es + (i1 < L ? i1 : 0)];
        }
        float rc0 = rn[cc0], rc1 = rn[cc1];
        uint4 A00 = xh4[(size_t)cc0 * 8 + q];
        uint4 A01 = xh4[(size_t)cc0 * 8 + 4 + q];
        uint4 A10 = xh4[(size_t)cc1 * 8 + q];
        uint4 A11 = xh4[(size_t)cc1 * 8 + 4 + q];

        for (int k = 0; k < nchw; ++k) {
            int base = (wid + 2 * k) << 5;
            bool more = (k + 1) < nchw;

            // Prefetch this wave's next chunk (+64 edges) column indices.
            int nc0, nc1;
            if (more) {
                int i0 = base + 64 + lo4, i1 = i0 + 16;
                nc0 = edge_col[es + (i0 < L ? i0 : 0)];
                nc1 = edge_col[es + (i1 < L ? i1 : 0)];
            } else { nc0 = cc0; nc1 = cc1; }

            v4f z0 = {0,0,0,0};
            z0 = __builtin_amdgcn_mfma_f32_16x16x32_f16(a0, u2h8(A00), z0, 0, 0, 0);
            z0 = __builtin_amdgcn_mfma_f32_16x16x32_f16(a1, u2h8(A01), z0, 0, 0, 0);
            v4f z1 = {0,0,0,0};
            z1 = __builtin_amdgcn_mfma_f32_16x16x32_f16(a0, u2h8(A10), z1, 0, 0, 0);
            z1 = __builtin_amdgcn_mfma_f32_16x16x32_f16(a1, u2h8(A11), z1, 0, 0, 0);

            {
                unsigned int colA = lo4 * 4, colB = (16 + lo4) * 4;
                char* pA = XCP + (4 * q) * XCP_PITCH;
                char* pB = XCP + (16 + 4 * q) * XCP_PITCH;
                *(unsigned int*)(pA + 0 * XCP_PITCH + colA) = A00.x;
                *(unsigned int*)(pA + 1 * XCP_PITCH + colA) = A00.y;
                *(unsigned int*)(pA + 2 * XCP_PITCH + colA) = A00.z;
                *(unsigned int*)(pA + 3 * XCP_PITCH + colA) = A00.w;
                *(unsigned int*)(pB + 0 * XCP_PITCH + colA) = A01.x;
                *(unsigned int*)(pB + 1 * XCP_PITCH + colA) = A01.y;
                *(unsigned int*)(pB + 2 * XCP_PITCH + colA) = A01.z;
                *(unsigned int*)(pB + 3 * XCP_PITCH + colA) = A01.w;
                *(unsigned int*)(pA + 0 * XCP_PITCH + colB) = A10.x;
                *(unsigned int*)(pA + 1 * XCP_PITCH + colB) = A10.y;
                *(unsigned int*)(pA + 2 * XCP_PITCH + colB) = A10.z;
                *(unsigned int*)(pA + 3 * XCP_PITCH + colB) = A10.w;
                *(unsigned int*)(pB + 0 * XCP_PITCH + colB) = A11.x;
                *(unsigned int*)(pB + 1 * XCP_PITCH + colB) = A11.y;
                *(unsigned int*)(pB + 2 * XCP_PITCH + colB) = A11.z;
                *(unsigned int*)(pB + 3 * XCP_PITCH + colB) = A11.w;
            }

            // Prefetch next chunk's features + norms.
            float nr0, nr1; uint4 B00, B01, B10, B11;
            if (more) {
                nr0 = rn[nc0]; nr1 = rn[nc1];
                B00 = xh4[(size_t)nc0 * 8 + q];
                B01 = xh4[(size_t)nc0 * 8 + 4 + q];
                B10 = xh4[(size_t)nc1 * 8 + q];
                B11 = xh4[(size_t)nc1 * 8 + 4 + q];
            } else {
                nr0 = rc0; nr1 = rc1;
                B00 = A00; B01 = A01; B10 = A10; B11 = A11;
            }

            int i0g = base + lo4, i1g = i0g + 16;
            float w00 = (i0g >= b0 && i0g < b1) ? __expf(brn0 * rc0 * z0[0] - shift) : 0.f;
            float w01 = (i0g >= b1 && i0g < b2) ? __expf(brn1 * rc0 * z0[1] - shift) : 0.f;
            float w02 = (i0g >= b2 && i0g < b3) ? __expf(brn2 * rc0 * z0[2] - shift) : 0.f;
            float w03 = (i0g >= b3 && i0g < b4) ? __expf(brn3 * rc0 * z0[3] - shift) : 0.f;
            float w10 = (i1g >= b0 && i1g < b1) ? __expf(brn0 * rc1 * z1[0] - shift) : 0.f;
            float w11 = (i1g >= b1 && i1g < b2) ? __expf(brn1 * rc1 * z1[1] - shift) : 0.f;
            float w12 = (i1g >= b2 && i1g < b3) ? __expf(brn2 * rc1 * z1[2] - shift) : 0.f;
            float w13 = (i1g >= b3 && i1g < b4) ? __expf(brn3 * rc1 * z1[3] - shift) : 0.f;
            l0 += w00 + w10; l1 += w01 + w11; l2 += w02 + w12; l3 += w03 + w13;

            {
                unsigned int cA = lo4 * 2, cB = (16 + lo4) * 2;
                char* pm = PL + (q * 4) * P_PITCH;
                *(_Float16*)(pm + 0 * P_PITCH + cA) = (_Float16)w00;
                *(_Float16*)(pm + 1 * P_PITCH + cA) = (_Float16)w01;
                *(_Float16*)(pm + 2 * P_PITCH + cA) = (_Float16)w02;
                *(_Float16*)(pm + 3 * P_PITCH + cA) = (_Float16)w03;
                *(_Float16*)(pm + 0 * P_PITCH + cB) = (_Float16)w10;
                *(_Float16*)(pm + 1 * P_PITCH + cB) = (_Float16)w11;
                *(_Float16*)(pm + 2 * P_PITCH + cB) = (_Float16)w12;
                *(_Float16*)(pm + 3 * P_PITCH + cB) = (_Float16)w13;
            }

            v8h pah = u2h8(*(const uint4*)(PL + lo4 * P_PITCH + q * 16));
            {
                const char* rp = XCP + (0 + (lo4 >> 1)) * XCP_PITCH + q * 32;
                uint4 da = *(const uint4*)rp;
                uint4 db = *(const uint4*)(rp + 16);
                uint4 bb = { __builtin_amdgcn_perm(da.y, da.x, selp),
                             __builtin_amdgcn_perm(da.w, da.z, selp),
                             __builtin_amdgcn_perm(db.y, db.x, selp),
                             __builtin_amdgcn_perm(db.w, db.z, selp) };
                o0 = __builtin_amdgcn_mfma_f32_16x16x32_f16(pah, u2h8(bb), o0, 0, 0, 0);
            }
            {
                const char* rp = XCP + (8 + (lo4 >> 1)) * XCP_PITCH + q * 32;
                uint4 da = *(const uint4*)rp;
                uint4 db = *(const uint4*)(rp + 16);
                uint4 bb = { __builtin_amdgcn_perm(da.y, da.x, selp),
                             __builtin_amdgcn_perm(da.w, da.z, selp),
                             __builtin_amdgcn_perm(db.y, db.x, selp),
                             __builtin_amdgcn_perm(db.w, db.z, selp) };
                o1 = __builtin_amdgcn_mfma_f32_16x16x32_f16(pah, u2h8(bb), o1, 0, 0, 0);
            }
            {
                const char* rp = XCP + (16 + (lo4 >> 1)) * XCP_PITCH + q * 32;
                uint4 da = *(const uint4*)rp;
                uint4 db = *(const uint4*)(rp + 16);
                uint4 bb = { __builtin_amdgcn_perm(da.y, da.x, selp),
                             __builtin_amdgcn_perm(da.w, da.z, selp),
                             __builtin_amdgcn_perm(db.y, db.x, selp),
                             __builtin_amdgcn_perm(db.w, db.z, selp) };
                o2 = __builtin_amdgcn_mfma_f32_16x16x32_f16(pah, u2h8(bb), o2, 0, 0, 0);
            }
            {
                const char* rp = XCP + (24 + (lo4 >> 1)) * XCP_PITCH + q * 32;
                uint4 da = *(const uint4*)rp;
                uint4 db = *(const uint4*)(rp + 16);
                uint4 bb = { __builtin_amdgcn_perm(da.y, da.x, selp),
                             __builtin_amdgcn_perm(da.w, da.z, selp),
                             __builtin_amdgcn_perm(db.y, db.x, selp),
                             __builtin_amdgcn_perm(db.w, db.z, selp) };
                o3 = __builtin_amdgcn_mfma_f32_16x16x32_f16(pah, u2h8(bb), o3, 0, 0, 0);
            }

            // Rotate pipeline state.
            cc0 = nc0; cc1 = nc1; rc0 = nr0; rc1 = nr1;
            A00 = B00; A01 = B01; A10 = B10; A11 = B11;
        }
    }

    // ---- cross-wave combine: wave1 dumps partials into its own LDS area ----
    if (wid == 1) {
        char* ST = XCP;  // wave1's private region, reused as scratch
        *(v4f*)(ST + lane * 80 +  0) = o0;
        *(v4f*)(ST + lane * 80 + 16) = o1;
        *(v4f*)(ST + lane * 80 + 32) = o2;
        *(v4f*)(ST + lane * 80 + 48) = o3;
        float4 lv = {l0, l1, l2, l3};
        *(float4*)(ST + lane * 80 + 64) = lv;
    }
    __syncthreads();
    if (wid == 1) return;
    {
        const char* ST = lds_raw + WAVE_LDS;
        o0 += *(const v4f*)(ST + lane * 80 +  0);
        o1 += *(const v4f*)(ST + lane * 80 + 16);
        o2 += *(const v4f*)(ST + lane * 80 + 32);
        o3 += *(const v4f*)(ST + lane * 80 + 48);
        float4 lv = *(const float4*)(ST + lane * 80 + 64);
        l0 += lv.x; l1 += lv.y; l2 += lv.z; l3 += lv.w;
    }

    #pragma unroll
    for (int off = 1; off < 16; off <<= 1) {
        l0 += __shfl_xor(l0, off, 64);
        l1 += __shfl_xor(l1, off, 64);
        l2 += __shfl_xor(l2, off, 64);
        l3 += __shfl_xor(l3, off, 64);
    }
    float i0 = l0 > 0.f ? 1.f / l0 : 0.f;
    float i1 = l1 > 0.f ? 1.f / l1 : 0.f;
    float i2 = l2 > 0.f ? 1.f / l2 : 0.f;
    float i3 = l3 > 0.f ? 1.f / l3 : 0.f;

    int m0 = rb;
    if (m0 + 0 < n_nodes) { float* p = out + (size_t)(m0 + 0) * 64 + lo4;
        p[0] = o0[0]*i0; p[16] = o1[0]*i0; p[32] = o2[0]*i0; p[48] = o3[0]*i0; }
    if (m0 + 1 < n_nodes) { float* p = out + (size_t)(m0 + 1) * 64 + lo4;
        p[0] = o0[1]*i1; p[16] = o1[1]*i1; p[32] = o2[1]*i1; p[48] = o3[1]*i1; }
    if (m0 + 2 < n_nodes) { float* p = out + (size_t)(m0 + 2) * 64 + lo4;
        p[0] = o0[2]*i2; p[16] = o1[2]*i2; p[32] = o2[2]*i2; p[48] = o3[2]*i2; }
    if (m0 + 3 < n_nodes) { float* p = out + (size_t)(m0 + 3) * 64 + lo4;
        p[0] = o0[3]*i3; p[16] = o1[3]*i3; p[32] = o2[3]*i3; p[48] = o3[3]*i3; }
}

extern "C" void kernel_launch(void* const* d_in, const int* in_sizes, int n_in,
                              void* d_out, int out_size, void* d_ws, size_t ws_size,
                              hipStream_t stream) {
    const float* x        = (const float*)d_in[0];
    const float* beta     = (const float*)d_in[1];
    const int*   edge_row = (const int*)d_in[2];
    const int*   edge_col = (const int*)d_in[3];
    float* out = (float*)d_out;

    int n_nodes = in_sizes[0] / D_FEAT;
    int n_edges = in_sizes[2];

    char* ws = (char*)d_ws;
    float* rn = (float*)ws;
    size_t off0 = ((size_t)n_nodes * sizeof(float) + 255) & ~(size_t)255;
    int* row_ptr = (int*)(ws + off0);
    size_t off1 = off0 + (((size_t)(n_nodes + 1) * sizeof(int) + 255) & ~(size_t)255);
    uint2* xh = (uint2*)(ws + off1);

    {
        int nb_prep = (n_nodes * 16 + 255) / 256;
        int nb_rp   = (n_edges + 255) / 256;
        agnn_prep<<<nb_prep + nb_rp, 256, 0, stream>>>(
            x, rn, xh, edge_row, row_ptr, n_nodes, n_edges, nb_prep);
    }
    {
        int tiles = (n_nodes + 15) / 16;
        agnn_fused<<<tiles, 128, 0, stream>>>(beta, edge_col, row_ptr,
                                              rn, (const uint4*)xh, out, n_nodes);
    }
}